// Round 7
// baseline (142.761 us; speedup 1.0000x reference)
//
#include <hip/hip_runtime.h>

// Problem constants
#define DIM 128
#define HID 256
#define K2LE 2.885390081777927f   // 2*log2(e): tanh(x) = 1 - 2/(exp2(K2LE*x)+1)
#define NTILES 16                 // HID / 16
#define BFPAD 136                 // bf16 LDS row stride (gemm kernel)

typedef __attribute__((ext_vector_type(8))) short bf16x8;   // 8 bf16 = 4 VGPRs
typedef __attribute__((ext_vector_type(4))) float f32x4;

__device__ __forceinline__ unsigned short f2bf(float f) {
    union { float f; unsigned u; } x; x.f = f;
    unsigned r = x.u + 0x7fffu + ((x.u >> 16) & 1u);   // RNE
    return (unsigned short)(r >> 16);
}
__device__ __forceinline__ float bflo(unsigned u) { return __uint_as_float(u << 16); }
__device__ __forceinline__ float bfhi(unsigned u) { return __uint_as_float(u & 0xffff0000u); }

__device__ __forceinline__ float sigmoid_fast(float x) {
    float t = __builtin_amdgcn_exp2f(-x * 1.4426950408889634f);
    return __builtin_amdgcn_rcpf(1.0f + t);
}

// All-reduce sum across a 16-lane DPP row — VALU pipe only, no LDS.
__device__ __forceinline__ float row16_allreduce(float x) {
    int t;
    t = __builtin_amdgcn_update_dpp(0, __float_as_int(x), 0xB1, 0xf, 0xf, true);
    x += __int_as_float(t);
    t = __builtin_amdgcn_update_dpp(0, __float_as_int(x), 0x4E, 0xf, 0xf, true);
    x += __int_as_float(t);
    t = __builtin_amdgcn_update_dpp(0, __float_as_int(x), 0x124, 0xf, 0xf, true);
    x += __int_as_float(t);
    t = __builtin_amdgcn_update_dpp(0, __float_as_int(x), 0x128, 0xf, 0xf, true);
    x += __int_as_float(t);
    return x;
}

// ---------------------------------------------------------------------------
// Prep (16 blocks x 256):
//   block 0: c2[j]  = K2LE*(pivot@W1 + b1)[j]              (legacy layout)
//            c2p/w2p: same values permuted to [m*16 + nt]  (march layout)
//   all:     W1f = bf16(K2LE*W1) in MFMA B-frag order
// ---------------------------------------------------------------------------
__global__ void k_prep(const float* __restrict__ pivot,
                       const float* __restrict__ W1,
                       const float* __restrict__ b1,
                       const float* __restrict__ w2,
                       float* __restrict__ c2,
                       float* __restrict__ c2p,
                       float* __restrict__ w2p,
                       uint4* __restrict__ W1f) {
    const int tid = threadIdx.x;
    if (blockIdx.x == 0) {
        float a = b1[tid];
#pragma unroll 8
        for (int d = 0; d < DIM; ++d) a = fmaf(pivot[d], W1[d * HID + tid], a);
        float cv = K2LE * a;
        c2[tid] = cv;
        const int pidx = (tid & 15) * 16 + (tid >> 4);   // col -> [m][nt]
        c2p[pidx] = cv;
        w2p[pidx] = w2[tid];
    }
    const int e  = blockIdx.x * 256 + tid;
    const int m  = e & 15;
    const int q  = (e >> 4) & 3;
    const int kk = (e >> 6) & 3;
    const int nt = e >> 8;
    const int n  = nt * 16 + m;
    const int k0 = kk * 32 + q * 8;
    unsigned w[4];
#pragma unroll
    for (int p = 0; p < 4; ++p) {
        unsigned lo = f2bf(W1[(k0 + 2 * p    ) * HID + n] * K2LE);
        unsigned hi = f2bf(W1[(k0 + 2 * p + 1) * HID + n] * K2LE);
        w[p] = lo | (hi << 16);
    }
    W1f[e] = make_uint4(w[0], w[1], w[2], w[3]);
}

// ---------------------------------------------------------------------------
// Kernel A: normalize + GEMM. 512 blocks x 256 thr; wave owns 16 rays.
//   rn_g [ray][128] bf16 (uint = 2 dims), g_buf [ray][m][nt] bf16.
// No __syncthreads needed: each wave reads only its own LDS rows.
// ---------------------------------------------------------------------------
__global__ __launch_bounds__(256, 4) void k_gemm(
    const float* __restrict__ r,
    const uint4* __restrict__ W1f,
    unsigned* __restrict__ rn_g,   // B*64 uints
    uint4* __restrict__ g_buf)     // B*32 uint4
{
    __shared__ unsigned short rnbf[64][BFPAD];

    const int tid  = threadIdx.x;
    const int lane = tid & 63;
    const int wave = tid >> 6;
    const int m    = lane & 15;
    const int q    = lane >> 4;
    const int rowb = blockIdx.x * 64 + wave * 16;

    // ---- Phase 1: load + normalize, stash bf16 to LDS + global ----
#pragma unroll 4
    for (int t = 0; t < 16; ++t) {
        const int row = rowb + t;
        float2 v = *(const float2*)&r[row * DIM + lane * 2];
        float ss = v.x * v.x + v.y * v.y;
#pragma unroll
        for (int msk = 32; msk >= 1; msk >>= 1) ss += __shfl_xor(ss, msk, 64);
        float inv = __builtin_amdgcn_rsqf(ss);
        unsigned pack = (unsigned)f2bf(v.x * inv) | ((unsigned)f2bf(v.y * inv) << 16);
        *(unsigned*)&rnbf[wave * 16 + t][lane * 2] = pack;
        rn_g[row * 64 + lane] = pack;
    }

    // ---- Phase 2: 16x256 GEMM via MFMA ----
    bf16x8 afrag[4];
#pragma unroll
    for (int kk = 0; kk < 4; ++kk)
        afrag[kk] = *(const bf16x8*)&rnbf[wave * 16 + m][kk * 32 + q * 8];

    const bf16x8* __restrict__ wf = (const bf16x8*)W1f;
    const int fb = q * 16 + m;
    unsigned pk[4][8];                 // [reg(ray)][nt/2] packed bf16 pairs
#pragma unroll
    for (int nt = 0; nt < NTILES; ++nt) {
        f32x4 a = {0.f, 0.f, 0.f, 0.f};
#pragma unroll
        for (int kk = 0; kk < 4; ++kk)
            a = __builtin_amdgcn_mfma_f32_16x16x32_bf16(
                    afrag[kk], wf[nt * 256 + kk * 64 + fb], a, 0, 0, 0);
#pragma unroll
        for (int reg = 0; reg < 4; ++reg) {
            unsigned h = f2bf(a[reg]);
            if (nt & 1) pk[reg][nt >> 1] |= (h << 16);
            else        pk[reg][nt >> 1]  = h;
        }
    }
#pragma unroll
    for (int reg = 0; reg < 4; ++reg) {
        const int ray = rowb + q * 4 + reg;
        uint4* p = g_buf + ray * 32 + m * 2;
        p[0] = make_uint4(pk[reg][0], pk[reg][1], pk[reg][2], pk[reg][3]);
        p[1] = make_uint4(pk[reg][4], pk[reg][5], pk[reg][6], pk[reg][7]);
    }
}

// ---------------------------------------------------------------------------
// Kernel B: ray march. 2048 blocks x 256 thr; 1 ray per 16-lane group,
// 16 cols/lane. Zero LDS, lean VGPR -> 8 waves/SIMD.
// ---------------------------------------------------------------------------
__global__ __launch_bounds__(256, 8) void k_march(
    const uint4* __restrict__ g_buf,   // [ray][m][nt] bf16
    const uint4* __restrict__ rn_g,    // [ray][128] bf16, 16 uint4/ray
    const float* __restrict__ s,
    const float* __restrict__ pivot,
    const float* __restrict__ c2p,     // [m*16+nt]
    const float* __restrict__ w2p,
    const float* __restrict__ b2,
    const int* __restrict__ n_iter_p,
    float* __restrict__ out)           // [B,128] f32
{
    const int tid  = threadIdx.x;
    const int lane = tid & 63;
    const int wave = tid >> 6;
    const int m    = lane & 15;
    const int q    = lane >> 4;
    const int ray  = blockIdx.x * 16 + wave * 4 + q;
    const int n_iter = *n_iter_p;

    // ---- load g (2x dwordx4, coalesced) and unpack to f32 ----
    uint4 ga = g_buf[ray * 32 + m * 2];
    uint4 gb = g_buf[ray * 32 + m * 2 + 1];
    float g[16];
    g[0]=bflo(ga.x); g[1]=bfhi(ga.x); g[2]=bflo(ga.y); g[3]=bfhi(ga.y);
    g[4]=bflo(ga.z); g[5]=bfhi(ga.z); g[6]=bflo(ga.w); g[7]=bfhi(ga.w);
    g[8]=bflo(gb.x); g[9]=bfhi(gb.x); g[10]=bflo(gb.y); g[11]=bfhi(gb.y);
    g[12]=bflo(gb.z); g[13]=bfhi(gb.z); g[14]=bflo(gb.w); g[15]=bfhi(gb.w);

    // ---- load permuted c2/w2 (contiguous 64 B per lane) ----
    float c[16], w[16];
#pragma unroll
    for (int i = 0; i < 4; ++i) {
        float4 cv = *(const float4*)(c2p + m * 16 + i * 4);
        float4 wv = *(const float4*)(w2p + m * 16 + i * 4);
        c[4*i]=cv.x; c[4*i+1]=cv.y; c[4*i+2]=cv.z; c[4*i+3]=cv.w;
        w[4*i]=wv.x; w[4*i+1]=wv.y; w[4*i+2]=wv.z; w[4*i+3]=wv.w;
    }
    float S = 0.f;
#pragma unroll
    for (int i = 0; i < 16; ++i) S += w[i];
    S = row16_allreduce(S);
    const float C0 = K2LE * (S + b2[0]);

    // ---- march ----
    float alpha = 0.f;
    for (int it = 0; it < n_iter; ++it) {
        float p = 0.f;
#pragma unroll
        for (int i = 0; i < 16; ++i) {
            float u = __builtin_amdgcn_rcpf(
                __builtin_amdgcn_exp2f(fmaf(alpha, g[i], c[i])) + 1.0f);
            p = fmaf(w[i], u, p);
        }
        p = row16_allreduce(p);
        float v = __builtin_amdgcn_rcpf(
            __builtin_amdgcn_exp2f(fmaf(-2.0f * K2LE, p, C0)) + 1.0f);
        alpha += fmaf(-0.1f, v, 0.1f);
    }

    // ---- epilogue: out[ray][8m..8m+8) = pivot + sigmoid(s)*alpha*rn ----
    const float sc = sigmoid_fast(s[ray]) * alpha;
    uint4 rl = rn_g[ray * 16 + m];     // FIXED: 16 uint4 per ray (was *8)
    float4 pv0 = *(const float4*)(pivot + m * 8);
    float4 pv1 = *(const float4*)(pivot + m * 8 + 4);
    float4 o0, o1;
    o0.x = fmaf(sc, bflo(rl.x), pv0.x);
    o0.y = fmaf(sc, bfhi(rl.x), pv0.y);
    o0.z = fmaf(sc, bflo(rl.y), pv0.z);
    o0.w = fmaf(sc, bfhi(rl.y), pv0.w);
    o1.x = fmaf(sc, bflo(rl.z), pv1.x);
    o1.y = fmaf(sc, bfhi(rl.z), pv1.y);
    o1.z = fmaf(sc, bflo(rl.w), pv1.z);
    o1.w = fmaf(sc, bfhi(rl.w), pv1.w);
    *(float4*)(out + ray * DIM + m * 8)     = o0;
    *(float4*)(out + ray * DIM + m * 8 + 4) = o1;
}

// ---------------------------------------------------------------------------
// Fallback (R5 fused kernel) — used only if workspace is too small.
// ---------------------------------------------------------------------------
__global__ __launch_bounds__(256, 4) void k_main_fused(
    const float* __restrict__ r, const float* __restrict__ s,
    const float* __restrict__ pivot, const float* __restrict__ w2,
    const float* __restrict__ b2, const int* __restrict__ n_iter_p,
    const float* __restrict__ c2, const uint4* __restrict__ W1f,
    float* __restrict__ out)
{
    __shared__ unsigned short rnbf[32][BFPAD];
    __shared__ float rnf[32][DIM];
    __shared__ float alpha_s[32];

    const int tid  = threadIdx.x;
    const int lane = tid & 63;
    const int wave = tid >> 6;
    const int pr   = wave >> 1;
    const int par  = wave & 1;
    const int m    = lane & 15;
    const int q    = lane >> 4;
    const int rowblk = blockIdx.x * 32;
    const int n_iter = *n_iter_p;

#pragma unroll
    for (int t = 0; t < 8; ++t) {
        const int lr = wave * 8 + t;
        float2 v = *(const float2*)&r[(rowblk + lr) * DIM + lane * 2];
        float ss = v.x * v.x + v.y * v.y;
#pragma unroll
        for (int msk = 32; msk >= 1; msk >>= 1) ss += __shfl_xor(ss, msk, 64);
        float inv = __builtin_amdgcn_rsqf(ss);
        float2 rn; rn.x = v.x * inv; rn.y = v.y * inv;
        *(float2*)&rnf[lr][lane * 2] = rn;
        unsigned pack = (unsigned)f2bf(rn.x) | ((unsigned)f2bf(rn.y) << 16);
        *(unsigned*)&rnbf[lr][lane * 2] = pack;
    }
    __syncthreads();

    bf16x8 afrag[4];
#pragma unroll
    for (int kk = 0; kk < 4; ++kk)
        afrag[kk] = *(const bf16x8*)&rnbf[pr * 16 + m][kk * 32 + q * 8];

    const bf16x8* __restrict__ wf = (const bf16x8*)W1f;
    const int fb = q * 16 + m;
    float gA[NTILES], gB[NTILES];
#pragma unroll
    for (int nt = 0; nt < NTILES; ++nt) {
        f32x4 a = {0.f, 0.f, 0.f, 0.f};
#pragma unroll
        for (int kk = 0; kk < 4; ++kk)
            a = __builtin_amdgcn_mfma_f32_16x16x32_bf16(
                    afrag[kk], wf[nt * 256 + kk * 64 + fb], a, 0, 0, 0);
        gA[nt] = a[par * 2 + 0];
        gB[nt] = a[par * 2 + 1];
    }
    float w2f[NTILES], c2f[NTILES];
#pragma unroll
    for (int nt = 0; nt < NTILES; ++nt) {
        w2f[nt] = w2[nt * 16 + m];
        c2f[nt] = c2[nt * 16 + m];
    }
    float S = 0.f;
#pragma unroll
    for (int nt = 0; nt < NTILES; ++nt) S += w2f[nt];
    S = row16_allreduce(S);
    const float C0 = K2LE * (S + b2[0]);

    float alphaA = 0.f, alphaB = 0.f;
    for (int it = 0; it < n_iter; ++it) {
        float pA = 0.f, pB = 0.f;
#pragma unroll
        for (int nt = 0; nt < NTILES; ++nt) {
            float uA = __builtin_amdgcn_rcpf(__builtin_amdgcn_exp2f(fmaf(alphaA, gA[nt], c2f[nt])) + 1.0f);
            float uB = __builtin_amdgcn_rcpf(__builtin_amdgcn_exp2f(fmaf(alphaB, gB[nt], c2f[nt])) + 1.0f);
            pA = fmaf(w2f[nt], uA, pA);
            pB = fmaf(w2f[nt], uB, pB);
        }
        pA = row16_allreduce(pA);
        pB = row16_allreduce(pB);
        float vA = __builtin_amdgcn_rcpf(__builtin_amdgcn_exp2f(fmaf(-2.0f * K2LE, pA, C0)) + 1.0f);
        float vB = __builtin_amdgcn_rcpf(__builtin_amdgcn_exp2f(fmaf(-2.0f * K2LE, pB, C0)) + 1.0f);
        alphaA += fmaf(-0.1f, vA, 0.1f);
        alphaB += fmaf(-0.1f, vB, 0.1f);
    }
    if (m == 0) {
        alpha_s[pr * 16 + q * 4 + par * 2 + 0] = alphaA;
        alpha_s[pr * 16 + q * 4 + par * 2 + 1] = alphaB;
    }
    __syncthreads();

    const float2 pv = *(const float2*)&pivot[lane * 2];
#pragma unroll
    for (int t = 0; t < 8; ++t) {
        const int lr  = wave * 8 + t;
        const int row = rowblk + lr;
        const float scale = sigmoid_fast(s[row]) * alpha_s[lr];
        float2 rn = *(const float2*)&rnf[lr][lane * 2];
        float2 o;
        o.x = fmaf(scale, rn.x, pv.x);
        o.y = fmaf(scale, rn.y, pv.y);
        *(float2*)&out[row * DIM + lane * 2] = o;
    }
}

extern "C" void kernel_launch(void* const* d_in, const int* in_sizes, int n_in,
                              void* d_out, int out_size, void* d_ws, size_t ws_size,
                              hipStream_t stream) {
    const float* r      = (const float*)d_in[0];
    const float* s      = (const float*)d_in[1];
    const float* pivot  = (const float*)d_in[2];
    const float* W1     = (const float*)d_in[3];
    const float* b1     = (const float*)d_in[4];
    const float* w2     = (const float*)d_in[5];
    const float* b2     = (const float*)d_in[6];
    const int*   n_iter = (const int*)d_in[7];
    float* out = (float*)d_out;

    const int B = in_sizes[0] / DIM;  // 32768

    char* ws = (char*)d_ws;
    float* c2   = (float*)(ws);            // 1 KB
    float* c2p  = (float*)(ws + 1024);     // 1 KB
    float* w2p  = (float*)(ws + 2048);     // 1 KB
    uint4* W1f  = (uint4*)(ws + 4096);     // 64 KB
    uint4* g_buf = (uint4*)(ws + 69632);                       // B*512 B
    unsigned* rn_g = (unsigned*)(ws + 69632 + (size_t)B * 512); // B*256 B

    const size_t need = 69632 + (size_t)B * 768;

    k_prep<<<16, 256, 0, stream>>>(pivot, W1, b1, w2, c2, c2p, w2p, W1f);
    if (ws_size >= need) {
        k_gemm<<<B / 64, 256, 0, stream>>>(r, W1f, rn_g, g_buf);
        k_march<<<B / 16, 256, 0, stream>>>(g_buf, (const uint4*)rn_g, s, pivot,
                                            c2p, w2p, b2, n_iter, out);
    } else {
        k_main_fused<<<B / 32, 256, 0, stream>>>(r, s, pivot, w2, b2, n_iter,
                                                 c2, W1f, out);
    }
}

// Round 8
// 123.437 us; speedup vs baseline: 1.1565x; 1.1565x over previous
//
#include <hip/hip_runtime.h>

// Problem constants
#define DIM 128
#define HID 256
#define K2LE 2.885390081777927f   // 2*log2(e): tanh(x) = 1 - 2/(exp2(K2LE*x)+1)
#define NTILES 16                 // HID / 16

typedef __attribute__((ext_vector_type(8))) short bf16x8;   // 8 bf16 = 4 VGPRs
typedef __attribute__((ext_vector_type(4))) float f32x4;

__device__ __forceinline__ unsigned short f2bf(float f) {
    union { float f; unsigned u; } x; x.f = f;
    unsigned r = x.u + 0x7fffu + ((x.u >> 16) & 1u);   // RNE
    return (unsigned short)(r >> 16);
}
__device__ __forceinline__ float bflo(unsigned u) { return __uint_as_float(u << 16); }
__device__ __forceinline__ float bfhi(unsigned u) { return __uint_as_float(u & 0xffff0000u); }

__device__ __forceinline__ float sigmoid_fast(float x) {
    float t = __builtin_amdgcn_exp2f(-x * 1.4426950408889634f);
    return __builtin_amdgcn_rcpf(1.0f + t);
}

// All-reduce sum across a 16-lane DPP row — VALU pipe only, no LDS.
// quad_perm(1,0,3,2)=0xB1, quad_perm(2,3,0,1)=0x4E, row_ror:4=0x124, row_ror:8=0x128
__device__ __forceinline__ float row16_allreduce(float x) {
    int t;
    t = __builtin_amdgcn_update_dpp(0, __float_as_int(x), 0xB1, 0xf, 0xf, true);
    x += __int_as_float(t);
    t = __builtin_amdgcn_update_dpp(0, __float_as_int(x), 0x4E, 0xf, 0xf, true);
    x += __int_as_float(t);
    t = __builtin_amdgcn_update_dpp(0, __float_as_int(x), 0x124, 0xf, 0xf, true);
    x += __int_as_float(t);
    t = __builtin_amdgcn_update_dpp(0, __float_as_int(x), 0x128, 0xf, 0xf, true);
    x += __int_as_float(t);
    return x;
}

// ---------------------------------------------------------------------------
// Prep (16 blocks x 256):
//   block 0: c2p/w2p[(col&15)*16 + (col>>4)] = K2LE*(pivot@W1+b1)[col], w2[col]
//   all:     W1f = bf16(K2LE*W1) in MFMA B-frag order:
//            entry e = nt*256 + kk*64 + q*16 + m holds W1[kk*32+q*8+j][nt*16+m]
// ---------------------------------------------------------------------------
__global__ void k_prep(const float* __restrict__ pivot,
                       const float* __restrict__ W1,
                       const float* __restrict__ b1,
                       const float* __restrict__ w2,
                       float* __restrict__ c2p,
                       float* __restrict__ w2p,
                       uint4* __restrict__ W1f) {
    const int tid = threadIdx.x;
    if (blockIdx.x == 0) {
        float a = b1[tid];
#pragma unroll 8
        for (int d = 0; d < DIM; ++d) a = fmaf(pivot[d], W1[d * HID + tid], a);
        const int pidx = (tid & 15) * 16 + (tid >> 4);   // col -> [m][i]
        c2p[pidx] = K2LE * a;
        w2p[pidx] = w2[tid];
    }
    const int e  = blockIdx.x * 256 + tid;
    const int m  = e & 15;
    const int q  = (e >> 4) & 3;
    const int kk = (e >> 6) & 3;
    const int nt = e >> 8;
    const int n  = nt * 16 + m;
    const int k0 = kk * 32 + q * 8;
    unsigned w[4];
#pragma unroll
    for (int p = 0; p < 4; ++p) {
        unsigned lo = f2bf(W1[(k0 + 2 * p    ) * HID + n] * K2LE);
        unsigned hi = f2bf(W1[(k0 + 2 * p + 1) * HID + n] * K2LE);
        w[p] = lo | (hi << 16);
    }
    W1f[e] = make_uint4(w[0], w[1], w[2], w[3]);
}

// ---------------------------------------------------------------------------
// Fused main: 2048 blocks x 256 thr, 16 rays/block.
//  - phase 1: lane(q,m) of wave w normalizes ray w*4+q (8 dims/lane, DPP reduce)
//  - phase 2: wave w MFMAs nt-group {4w..4w+3} for ALL 16 rays -> W1f read
//             exactly once per block; D goes to a 16 KB LDS exchange buffer
//  - phase 3: lane(q,m) marches ray w*4+q with cols {i*16+m}; alpha per-lane,
//             DPP row16 reduction; zero LDS traffic in the loop
//  - phase 4: epilogue from LDS bf16 rn
// LDS = 4 KB rn + 16 KB g = 20 KB -> 8 blocks/CU; VGPR<=64 -> 32 waves/CU.
// ---------------------------------------------------------------------------
__global__ __launch_bounds__(256, 8) void k_main(
    const float* __restrict__ r,      // [B,128]
    const float* __restrict__ s,      // [B]
    const float* __restrict__ pivot,  // [128]
    const float* __restrict__ c2p,    // [256] permuted K2LE*(pivot@W1+b1)
    const float* __restrict__ w2p,    // [256] permuted w2
    const float* __restrict__ b2,     // [1]
    const int* __restrict__ n_iter_p, // [1]
    const uint4* __restrict__ W1f,    // frag-ordered bf16 K2LE*W1
    float* __restrict__ out)          // [B,128]
{
    __shared__ unsigned short rnbf[16][128];  // 4 KB  [ray][k] bf16
    __shared__ float g_x[16][HID];            // 16 KB [ray][col] f32 exchange

    const int tid   = threadIdx.x;
    const int lane  = tid & 63;
    const int wave  = tid >> 6;        // 0..3: nt-group AND ray-group
    const int m     = lane & 15;
    const int q     = lane >> 4;
    const int ray_l = wave * 4 + q;    // this lane's ray (phases 1,3,4)
    const int ray_g = blockIdx.x * 16 + ray_l;
    const int n_iter = *n_iter_p;

    // ---- Phase 1: normalize ray ray_l; lane handles dims m*8..m*8+8 ----
    float4 v0 = *(const float4*)&r[ray_g * DIM + m * 8];
    float4 v1 = *(const float4*)&r[ray_g * DIM + m * 8 + 4];
    float ss = v0.x*v0.x + v0.y*v0.y + v0.z*v0.z + v0.w*v0.w
             + v1.x*v1.x + v1.y*v1.y + v1.z*v1.z + v1.w*v1.w;
    ss = row16_allreduce(ss);
    const float inv = __builtin_amdgcn_rsqf(ss);
    unsigned p0 = (unsigned)f2bf(v0.x*inv) | ((unsigned)f2bf(v0.y*inv) << 16);
    unsigned p1 = (unsigned)f2bf(v0.z*inv) | ((unsigned)f2bf(v0.w*inv) << 16);
    unsigned p2 = (unsigned)f2bf(v1.x*inv) | ((unsigned)f2bf(v1.y*inv) << 16);
    unsigned p3 = (unsigned)f2bf(v1.z*inv) | ((unsigned)f2bf(v1.w*inv) << 16);
    *(uint4*)&rnbf[ray_l][m * 8] = make_uint4(p0, p1, p2, p3);
    __syncthreads();

    // ---- Phase 2: wave w computes nt = 4w..4w+3 for all 16 rays ----
    bf16x8 afrag[4];
#pragma unroll
    for (int kk = 0; kk < 4; ++kk)
        afrag[kk] = *(const bf16x8*)&rnbf[m][kk * 32 + q * 8];

    const bf16x8* __restrict__ wf = (const bf16x8*)W1f;
    const int fb = q * 16 + m;
#pragma unroll
    for (int t = 0; t < 4; ++t) {
        const int nt = wave * 4 + t;
        f32x4 a = {0.f, 0.f, 0.f, 0.f};
#pragma unroll
        for (int kk = 0; kk < 4; ++kk)
            a = __builtin_amdgcn_mfma_f32_16x16x32_bf16(
                    afrag[kk], wf[nt * 256 + kk * 64 + fb], a, 0, 0, 0);
        // D: row(ray) = q*4+reg, col = nt*16+m  (m89-verified layout)
#pragma unroll
        for (int r4 = 0; r4 < 4; ++r4)
            g_x[q * 4 + r4][nt * 16 + m] = a[r4];
    }
    __syncthreads();

    // ---- Phase 3 setup: lane's 16 cols {i*16+m} of its ray ----
    float g[16], c[16], w[16];
#pragma unroll
    for (int i = 0; i < 16; ++i) g[i] = g_x[ray_l][i * 16 + m];
#pragma unroll
    for (int i = 0; i < 4; ++i) {
        float4 cv = *(const float4*)(c2p + m * 16 + i * 4);
        float4 wv = *(const float4*)(w2p + m * 16 + i * 4);
        c[4*i]=cv.x; c[4*i+1]=cv.y; c[4*i+2]=cv.z; c[4*i+3]=cv.w;
        w[4*i]=wv.x; w[4*i+1]=wv.y; w[4*i+2]=wv.z; w[4*i+3]=wv.w;
    }
    float S = 0.f;
#pragma unroll
    for (int i = 0; i < 16; ++i) S += w[i];
    S = row16_allreduce(S);
    const float C0 = K2LE * (S + b2[0]);

    // ---- Phase 3: march (alpha per-lane, uniform across the 16-lane row) ----
    float alpha = 0.f;
    for (int it = 0; it < n_iter; ++it) {
        float p = 0.f;
#pragma unroll
        for (int i = 0; i < 16; ++i) {
            float u = __builtin_amdgcn_rcpf(
                __builtin_amdgcn_exp2f(fmaf(alpha, g[i], c[i])) + 1.0f);
            p = fmaf(w[i], u, p);
        }
        p = row16_allreduce(p);
        float v = __builtin_amdgcn_rcpf(
            __builtin_amdgcn_exp2f(fmaf(-2.0f * K2LE, p, C0)) + 1.0f);
        alpha += fmaf(-0.1f, v, 0.1f);
    }

    // ---- Phase 4: out[ray][m*8..+8) = pivot + sigmoid(s)*alpha*rn ----
    const float sc = sigmoid_fast(s[ray_g]) * alpha;
    uint4 rl = *(const uint4*)&rnbf[ray_l][m * 8];
    float4 pv0 = *(const float4*)(pivot + m * 8);
    float4 pv1 = *(const float4*)(pivot + m * 8 + 4);
    float4 o0, o1;
    o0.x = fmaf(sc, bflo(rl.x), pv0.x);
    o0.y = fmaf(sc, bfhi(rl.x), pv0.y);
    o0.z = fmaf(sc, bflo(rl.y), pv0.z);
    o0.w = fmaf(sc, bfhi(rl.y), pv0.w);
    o1.x = fmaf(sc, bflo(rl.z), pv1.x);
    o1.y = fmaf(sc, bfhi(rl.z), pv1.y);
    o1.z = fmaf(sc, bflo(rl.w), pv1.z);
    o1.w = fmaf(sc, bfhi(rl.w), pv1.w);
    *(float4*)(out + ray_g * DIM + m * 8)     = o0;
    *(float4*)(out + ray_g * DIM + m * 8 + 4) = o1;
}

extern "C" void kernel_launch(void* const* d_in, const int* in_sizes, int n_in,
                              void* d_out, int out_size, void* d_ws, size_t ws_size,
                              hipStream_t stream) {
    const float* r      = (const float*)d_in[0];
    const float* s      = (const float*)d_in[1];
    const float* pivot  = (const float*)d_in[2];
    const float* W1     = (const float*)d_in[3];
    const float* b1     = (const float*)d_in[4];
    const float* w2     = (const float*)d_in[5];
    const float* b2     = (const float*)d_in[6];
    const int*   n_iter = (const int*)d_in[7];
    float* out = (float*)d_out;

    const int B = in_sizes[0] / DIM;  // 32768

    char* ws = (char*)d_ws;
    float* c2p = (float*)(ws);             // 1 KB
    float* w2p = (float*)(ws + 1024);      // 1 KB
    uint4* W1f = (uint4*)(ws + 4096);      // 64 KB

    k_prep<<<16, 256, 0, stream>>>(pivot, W1, b1, w2, c2p, w2p, W1f);
    k_main<<<B / 16, 256, 0, stream>>>(r, s, pivot, c2p, w2p, b2, n_iter,
                                       W1f, out);
}

// Round 9
// 122.515 us; speedup vs baseline: 1.1653x; 1.0075x over previous
//
#include <hip/hip_runtime.h>

// Problem constants
#define DIM 128
#define HID 256
#define K2LE 2.885390081777927f   // 2*log2(e): tanh(x) = 1 - 2/(exp2(K2LE*x)+1)
#define NTILES 16                 // HID / 16
#define RNPAD 136                 // rnbf row stride (bf16 elems): +16B kills 16-way
#define GXPAD 260                 // g_x row stride (f32): +16B spreads banks

typedef __attribute__((ext_vector_type(8))) short bf16x8;   // 8 bf16 = 4 VGPRs
typedef __attribute__((ext_vector_type(4))) float f32x4;

__device__ __forceinline__ unsigned short f2bf(float f) {
    union { float f; unsigned u; } x; x.f = f;
    unsigned r = x.u + 0x7fffu + ((x.u >> 16) & 1u);   // RNE
    return (unsigned short)(r >> 16);
}
__device__ __forceinline__ float bflo(unsigned u) { return __uint_as_float(u << 16); }
__device__ __forceinline__ float bfhi(unsigned u) { return __uint_as_float(u & 0xffff0000u); }

__device__ __forceinline__ float sigmoid_fast(float x) {
    float t = __builtin_amdgcn_exp2f(-x * 1.4426950408889634f);
    return __builtin_amdgcn_rcpf(1.0f + t);
}

// All-reduce sum across a 16-lane DPP row — VALU pipe only, no LDS.
__device__ __forceinline__ float row16_allreduce(float x) {
    int t;
    t = __builtin_amdgcn_update_dpp(0, __float_as_int(x), 0xB1, 0xf, 0xf, true);
    x += __int_as_float(t);
    t = __builtin_amdgcn_update_dpp(0, __float_as_int(x), 0x4E, 0xf, 0xf, true);
    x += __int_as_float(t);
    t = __builtin_amdgcn_update_dpp(0, __float_as_int(x), 0x124, 0xf, 0xf, true);
    x += __int_as_float(t);
    t = __builtin_amdgcn_update_dpp(0, __float_as_int(x), 0x128, 0xf, 0xf, true);
    x += __int_as_float(t);
    return x;
}

// ---------------------------------------------------------------------------
// Prep (16 blocks x 256):
//   block 0: c2p/w2p[(col&15)*16 + (col>>4)] = K2LE*(pivot@W1+b1)[col], w2[col]
//   all:     W1f = bf16(K2LE*W1) in MFMA B-frag order
// ---------------------------------------------------------------------------
__global__ void k_prep(const float* __restrict__ pivot,
                       const float* __restrict__ W1,
                       const float* __restrict__ b1,
                       const float* __restrict__ w2,
                       float* __restrict__ c2p,
                       float* __restrict__ w2p,
                       uint4* __restrict__ W1f) {
    const int tid = threadIdx.x;
    if (blockIdx.x == 0) {
        float a = b1[tid];
#pragma unroll 8
        for (int d = 0; d < DIM; ++d) a = fmaf(pivot[d], W1[d * HID + tid], a);
        const int pidx = (tid & 15) * 16 + (tid >> 4);   // col -> [m][i]
        c2p[pidx] = K2LE * a;
        w2p[pidx] = w2[tid];
    }
    const int e  = blockIdx.x * 256 + tid;
    const int m  = e & 15;
    const int q  = (e >> 4) & 3;
    const int kk = (e >> 6) & 3;
    const int nt = e >> 8;
    const int n  = nt * 16 + m;
    const int k0 = kk * 32 + q * 8;
    unsigned w[4];
#pragma unroll
    for (int p = 0; p < 4; ++p) {
        unsigned lo = f2bf(W1[(k0 + 2 * p    ) * HID + n] * K2LE);
        unsigned hi = f2bf(W1[(k0 + 2 * p + 1) * HID + n] * K2LE);
        w[p] = lo | (hi << 16);
    }
    W1f[e] = make_uint4(w[0], w[1], w[2], w[3]);
}

// ---------------------------------------------------------------------------
// Fused main: 2048 blocks x 256 thr, 16 rays/block.
//  phase 1: lane(q,m) of wave w normalizes ray w*4+q (8 dims/lane, DPP reduce)
//  phase 2: wave w MFMAs nt-group {4w..4w+3} for all 16 rays (W1f read once
//           per block); D -> padded LDS exchange
//  phase 3: lane(q,m) marches ray w*4+q, cols {i*16+m}; quad-rcp sigmoid,
//           DPP row16 reduce; zero LDS in the loop
//  phase 4: epilogue from LDS bf16 rn
// ---------------------------------------------------------------------------
__global__ __launch_bounds__(256, 6) void k_main(
    const float* __restrict__ r,      // [B,128]
    const float* __restrict__ s,      // [B]
    const float* __restrict__ pivot,  // [128]
    const float* __restrict__ c2p,    // [256] permuted K2LE*(pivot@W1+b1)
    const float* __restrict__ w2p,    // [256] permuted w2
    const float* __restrict__ b2,     // [1]
    const int* __restrict__ n_iter_p, // [1]
    const uint4* __restrict__ W1f,    // frag-ordered bf16 K2LE*W1
    float* __restrict__ out)          // [B,128]
{
    __shared__ unsigned short rnbf[16][RNPAD];  // 4.25 KB [ray][k] bf16, padded
    __shared__ float g_x[16][GXPAD];            // 16.25 KB [ray][col] f32, padded

    const int tid   = threadIdx.x;
    const int lane  = tid & 63;
    const int wave  = tid >> 6;        // 0..3: nt-group AND ray-group
    const int m     = lane & 15;
    const int q     = lane >> 4;
    const int ray_l = wave * 4 + q;    // this lane's ray (phases 1,3,4)
    const int ray_g = blockIdx.x * 16 + ray_l;
    const int n_iter = *n_iter_p;

    // ---- Phase 1: load r (HBM/L3) + issue param loads early to overlap ----
    float4 v0 = *(const float4*)&r[ray_g * DIM + m * 8];
    float4 v1 = *(const float4*)&r[ray_g * DIM + m * 8 + 4];
    const float sv  = s[ray_g];                      // hoisted for epilogue
    float c[16], w[16];
#pragma unroll
    for (int i = 0; i < 4; ++i) {                    // hoisted param loads
        float4 cv = *(const float4*)(c2p + m * 16 + i * 4);
        float4 wv = *(const float4*)(w2p + m * 16 + i * 4);
        c[4*i]=cv.x; c[4*i+1]=cv.y; c[4*i+2]=cv.z; c[4*i+3]=cv.w;
        w[4*i]=wv.x; w[4*i+1]=wv.y; w[4*i+2]=wv.z; w[4*i+3]=wv.w;
    }
    const float b2v = b2[0];

    float ss = v0.x*v0.x + v0.y*v0.y + v0.z*v0.z + v0.w*v0.w
             + v1.x*v1.x + v1.y*v1.y + v1.z*v1.z + v1.w*v1.w;
    ss = row16_allreduce(ss);
    const float inv = __builtin_amdgcn_rsqf(ss);
    unsigned p0 = (unsigned)f2bf(v0.x*inv) | ((unsigned)f2bf(v0.y*inv) << 16);
    unsigned p1 = (unsigned)f2bf(v0.z*inv) | ((unsigned)f2bf(v0.w*inv) << 16);
    unsigned p2 = (unsigned)f2bf(v1.x*inv) | ((unsigned)f2bf(v1.y*inv) << 16);
    unsigned p3 = (unsigned)f2bf(v1.z*inv) | ((unsigned)f2bf(v1.w*inv) << 16);
    *(uint4*)&rnbf[ray_l][m * 8] = make_uint4(p0, p1, p2, p3);
    __syncthreads();

    // ---- Phase 2: wave w computes nt = 4w..4w+3 for all 16 rays ----
    bf16x8 afrag[4];
#pragma unroll
    for (int kk = 0; kk < 4; ++kk)
        afrag[kk] = *(const bf16x8*)&rnbf[m][kk * 32 + q * 8];

    const bf16x8* __restrict__ wf = (const bf16x8*)W1f;
    const int fb = q * 16 + m;
#pragma unroll
    for (int t = 0; t < 4; ++t) {
        const int nt = wave * 4 + t;
        f32x4 a = {0.f, 0.f, 0.f, 0.f};
#pragma unroll
        for (int kk = 0; kk < 4; ++kk)
            a = __builtin_amdgcn_mfma_f32_16x16x32_bf16(
                    afrag[kk], wf[nt * 256 + kk * 64 + fb], a, 0, 0, 0);
        // D: row(ray) = q*4+reg, col = nt*16+m  (m89-verified layout)
#pragma unroll
        for (int r4 = 0; r4 < 4; ++r4)
            g_x[q * 4 + r4][nt * 16 + m] = a[r4];
    }

    // S/C0 while the exchange settles (uses regs only)
    float S = 0.f;
#pragma unroll
    for (int i = 0; i < 16; ++i) S += w[i];
    S = row16_allreduce(S);
    const float C0 = K2LE * (S + b2v);
    __syncthreads();

    // ---- Phase 3 setup: lane's 16 cols {i*16+m} of its ray ----
    float g[16];
#pragma unroll
    for (int i = 0; i < 16; ++i) g[i] = g_x[ray_l][i * 16 + m];

    // ---- Phase 3: march. Quad-rcp: sum_{i in quad} w_i/A_i,  A_i = 1+exp2(arg_i)
    //      = (n01*P23 + n23*P01) / (P01*P23)  -> 1 rcp per 4 sigmoids.
    //      den->inf saturates the quad's contribution to 0 (correct limit).
    float alpha = 0.f;
    for (int it = 0; it < n_iter; ++it) {
        float p = 0.f;
#pragma unroll
        for (int qd = 0; qd < 4; ++qd) {
            const int b = qd * 4;
            float A0 = __builtin_amdgcn_exp2f(fmaf(alpha, g[b+0], c[b+0])) + 1.0f;
            float A1 = __builtin_amdgcn_exp2f(fmaf(alpha, g[b+1], c[b+1])) + 1.0f;
            float A2 = __builtin_amdgcn_exp2f(fmaf(alpha, g[b+2], c[b+2])) + 1.0f;
            float A3 = __builtin_amdgcn_exp2f(fmaf(alpha, g[b+3], c[b+3])) + 1.0f;
            float P01 = A0 * A1;
            float P23 = A2 * A3;
            float n01 = fmaf(w[b+0], A1, w[b+1] * A0);
            float n23 = fmaf(w[b+2], A3, w[b+3] * A2);
            float num = fmaf(n01, P23, n23 * P01);
            float den = P01 * P23;
            p = fmaf(num, __builtin_amdgcn_rcpf(den), p);
        }
        p = row16_allreduce(p);
        float v = __builtin_amdgcn_rcpf(
            __builtin_amdgcn_exp2f(fmaf(-2.0f * K2LE, p, C0)) + 1.0f);
        alpha += fmaf(-0.1f, v, 0.1f);
    }

    // ---- Phase 4: out[ray][m*8..+8) = pivot + sigmoid(s)*alpha*rn ----
    const float sc = sigmoid_fast(sv) * alpha;
    uint4 rl = *(const uint4*)&rnbf[ray_l][m * 8];
    float4 pv0 = *(const float4*)(pivot + m * 8);
    float4 pv1 = *(const float4*)(pivot + m * 8 + 4);
    float4 o0, o1;
    o0.x = fmaf(sc, bflo(rl.x), pv0.x);
    o0.y = fmaf(sc, bfhi(rl.x), pv0.y);
    o0.z = fmaf(sc, bflo(rl.y), pv0.z);
    o0.w = fmaf(sc, bfhi(rl.y), pv0.w);
    o1.x = fmaf(sc, bflo(rl.z), pv1.x);
    o1.y = fmaf(sc, bfhi(rl.z), pv1.y);
    o1.z = fmaf(sc, bflo(rl.w), pv1.z);
    o1.w = fmaf(sc, bfhi(rl.w), pv1.w);
    *(float4*)(out + ray_g * DIM + m * 8)     = o0;
    *(float4*)(out + ray_g * DIM + m * 8 + 4) = o1;
}

extern "C" void kernel_launch(void* const* d_in, const int* in_sizes, int n_in,
                              void* d_out, int out_size, void* d_ws, size_t ws_size,
                              hipStream_t stream) {
    const float* r      = (const float*)d_in[0];
    const float* s      = (const float*)d_in[1];
    const float* pivot  = (const float*)d_in[2];
    const float* W1     = (const float*)d_in[3];
    const float* b1     = (const float*)d_in[4];
    const float* w2     = (const float*)d_in[5];
    const float* b2     = (const float*)d_in[6];
    const int*   n_iter = (const int*)d_in[7];
    float* out = (float*)d_out;

    const int B = in_sizes[0] / DIM;  // 32768

    char* ws = (char*)d_ws;
    float* c2p = (float*)(ws);             // 1 KB
    float* w2p = (float*)(ws + 1024);      // 1 KB
    uint4* W1f = (uint4*)(ws + 4096);      // 64 KB

    k_prep<<<16, 256, 0, stream>>>(pivot, W1, b1, w2, c2p, w2p, W1f);
    k_main<<<B / 16, 256, 0, stream>>>(r, s, pivot, c2p, w2p, b2, n_iter,
                                       W1f, out);
}